// Round 3
// baseline (703.751 us; speedup 1.0000x reference)
//
#include <hip/hip_runtime.h>

#define T_TOK 4096
#define H_DIM 512
#define F_DIM 2048
#define N_EXP 16
#define N_SH  2
#define TOPK  4

typedef __attribute__((ext_vector_type(4))) float f32x4;
typedef __attribute__((ext_vector_type(8))) short bf16x8;

__device__ __forceinline__ unsigned short f2bf(float f){
  union { float f; unsigned u; } a; a.f = f;
  unsigned u = a.u;
  return (unsigned short)((u + 0x7fffu + ((u >> 16) & 1u)) >> 16);
}

#define GLD16(gsrc, ldst) \
  __builtin_amdgcn_global_load_lds((const __attribute__((address_space(1))) unsigned int*)(gsrc), \
                                   (__attribute__((address_space(3))) unsigned int*)(ldst), 16, 0, 0)

// ---------------- convert x: f32 -> bf16 ----------------
__global__ void moe_convert_x(const float4* __restrict__ src, ushort4* __restrict__ dst){
  int i = blockIdx.x * 256 + threadIdx.x;       // T*H/4 = 524288 total
  float4 v = src[i];
  ushort4 o;
  o.x = f2bf(v.x); o.y = f2bf(v.y); o.z = f2bf(v.z); o.w = f2bf(v.w);
  dst[i] = o;
}

// ---------------- transpose + convert: src[R][C] f32 -> dst[C][R] bf16 ----------------
__global__ void moe_transpose(const float* __restrict__ src, unsigned short* __restrict__ dst,
                              int R, int C){
  __shared__ float tile[64][65];
  size_t matoff = (size_t)blockIdx.z * (size_t)R * (size_t)C;
  src += matoff; dst += matoff;
  int c0 = blockIdx.x * 64, r0 = blockIdx.y * 64;
  int t = threadIdx.x;
  #pragma unroll
  for (int i = 0; i < 16; ++i){
    int idx = i * 256 + t; int r = idx >> 6, c = idx & 63;
    tile[r][c] = src[(size_t)(r0 + r) * C + (c0 + c)];
  }
  __syncthreads();
  #pragma unroll
  for (int i = 0; i < 16; ++i){
    int idx = i * 256 + t; int r = idx >> 6, c = idx & 63;
    dst[(size_t)(c0 + r) * R + (r0 + c)] = f2bf(tile[c][r]);
  }
}

// ---------------- gating (fp64): softmax -> top4 -> softmax(top4) ----------------
__global__ void moe_gate(const float* __restrict__ x, const float* __restrict__ gw,
                         int* __restrict__ tki, float* __restrict__ tkw,
                         int* __restrict__ counts){
  int t = blockIdx.x;
  int lane = threadIdx.x;   // 64
  const float4* xr = (const float4*)(x + (size_t)t * H_DIM + lane * 8);
  float4 x0 = xr[0], x1 = xr[1];
  double xd[8] = {x0.x, x0.y, x0.z, x0.w, x1.x, x1.y, x1.z, x1.w};
  __shared__ double probs[N_EXP];
  for (int e = 0; e < N_EXP; ++e){
    const float4* wr = (const float4*)(gw + (size_t)e * H_DIM + lane * 8);
    float4 w0 = wr[0], w1 = wr[1];
    double wd[8] = {w0.x, w0.y, w0.z, w0.w, w1.x, w1.y, w1.z, w1.w};
    double s = 0.0;
    #pragma unroll
    for (int j = 0; j < 8; ++j) s = fma(xd[j], wd[j], s);
    #pragma unroll
    for (int o = 32; o; o >>= 1) s += __shfl_xor(s, o);
    if (lane == 0) probs[e] = s;
  }
  __syncthreads();
  if (lane == 0){
    double p[N_EXP];
    double m = -1e300;
    #pragma unroll
    for (int e = 0; e < N_EXP; ++e){ p[e] = probs[e]; m = fmax(m, p[e]); }
    double Z = 0.0;
    #pragma unroll
    for (int e = 0; e < N_EXP; ++e){ p[e] = exp(p[e] - m); Z += p[e]; }
    double inv = 1.0 / Z;
    #pragma unroll
    for (int e = 0; e < N_EXP; ++e) p[e] *= inv;
    int sel[TOPK]; double sv[TOPK];
    unsigned used = 0;
    for (int k = 0; k < TOPK; ++k){
      int best = -1; double bv = -1.0;
      #pragma unroll
      for (int e = 0; e < N_EXP; ++e)
        if (!((used >> e) & 1u) && p[e] > bv){ bv = p[e]; best = e; }
      used |= 1u << best; sel[k] = best; sv[k] = bv;
    }
    // second softmax over the selected probabilities.
    // NOTE: save the max BEFORE the exp loop (sv[0] was being overwritten
    // at k=0 and then read by k=1..3 — the round-1/2 absmax=0.298 bug).
    double m0 = sv[0];
    double Z2 = 0.0;
    #pragma unroll
    for (int k = 0; k < TOPK; ++k){ sv[k] = exp(sv[k] - m0); Z2 += sv[k]; }
    double i2 = 1.0 / Z2;
    #pragma unroll
    for (int k = 0; k < TOPK; ++k){
      tki[t * TOPK + k] = sel[k];
      tkw[t * TOPK + k] = (float)(sv[k] * i2);
      atomicAdd(&counts[sel[k]], 1);
    }
  }
}

// ---------------- prefix offsets (1 thread) ----------------
__global__ void moe_offsets(const int* __restrict__ counts, int* __restrict__ offs,
                            int* __restrict__ cursor){
  if (threadIdx.x == 0){
    int a = 0;
    for (int e = 0; e < N_EXP; ++e){ offs[e] = a; cursor[e] = a; a += counts[e]; }
  }
}

// ---------------- build per-expert row lists ----------------
__global__ void moe_build_rows(const int* __restrict__ tki, const float* __restrict__ tkw,
                               int* __restrict__ cursor, int* __restrict__ rows,
                               float* __restrict__ roww){
  int t = blockIdx.x * 256 + threadIdx.x;
  if (t >= T_TOK) return;
  for (int k = 0; k < TOPK; ++k){
    int e = tki[t * TOPK + k];
    int pos = atomicAdd(&cursor[e], 1);
    rows[pos] = t;
    roww[pos] = tkw[t * TOPK + k];
  }
}

// ---------------- grouped GEMM1: h = gelu(X @ W1 + b1), bf16 out ----------------
__global__ __launch_bounds__(256, 2) void moe_gemm1(
    const unsigned short* __restrict__ xb,
    const unsigned short* __restrict__ rw1T,   // [E][F][H]
    const unsigned short* __restrict__ sw1T,   // [2][F][H]
    const float* __restrict__ rb1, const float* __restrict__ sb1,
    const int* __restrict__ counts, const int* __restrict__ offs,
    const int* __restrict__ rows,
    unsigned short* __restrict__ h_rout, unsigned short* __restrict__ h_sh){
  constexpr int K  = H_DIM;   // 512
  constexpr int NK = K / 64;  // 8
  int job = blockIdx.z;
  int M; const int* rmap; const unsigned short* wT; const float* bias; unsigned short* hout;
  if (job < N_EXP){
    M = counts[job];
    int base = offs[job];
    rmap = rows + base;
    wT = rw1T + (size_t)job * F_DIM * H_DIM;
    bias = rb1 + job * F_DIM;
    hout = h_rout + (size_t)base * F_DIM;
  } else {
    int s = job - N_EXP;
    M = T_TOK; rmap = nullptr;
    wT = sw1T + (size_t)s * F_DIM * H_DIM;
    bias = sb1 + s * F_DIM;
    hout = h_sh + (size_t)s * T_TOK * F_DIM;
  }
  int m0 = blockIdx.y * 128;
  if (m0 >= M) return;
  int n0 = blockIdx.x * 128;

  __shared__ char smem[65536];
  int tid = threadIdx.x;
  int wave = tid >> 6, lane = tid & 63;
  int wm = wave >> 1, wn = wave & 1;

  const unsigned short* asrc[4];
  const unsigned short* bsrc[4];
  int srow = tid >> 3;   // 0..31
  int slot = tid & 7;
  #pragma unroll
  for (int r = 0; r < 4; ++r){
    int row = r * 32 + srow;
    int gr = m0 + row; if (gr > M - 1) gr = M - 1;
    int tok = rmap ? rmap[gr] : gr;
    asrc[r] = xb + (size_t)tok * H_DIM + ((slot ^ (row & 7)) << 3);
    bsrc[r] = wT + (size_t)(n0 + row) * K + ((slot ^ (row & 7)) << 3);
  }

  f32x4 acc[4][4];
  #pragma unroll
  for (int i = 0; i < 4; ++i)
    #pragma unroll
    for (int j = 0; j < 4; ++j) acc[i][j] = (f32x4)0.f;

  auto stage = [&](int buf, int k0){
    char* base = smem + buf * 32768;
    #pragma unroll
    for (int r = 0; r < 4; ++r) GLD16(asrc[r] + k0, base + r * 4096 + wave * 1024);
    #pragma unroll
    for (int r = 0; r < 4; ++r) GLD16(bsrc[r] + k0, base + 16384 + r * 4096 + wave * 1024);
  };

  stage(0, 0);
  int buf = 0;
  for (int kt = 0; kt < NK; ++kt){
    __syncthreads();
    if (kt + 1 < NK) stage(buf ^ 1, (kt + 1) * 64);
    const char* A = smem + buf * 32768;
    const char* B = A + 16384;
    #pragma unroll
    for (int ks = 0; ks < 2; ++ks){
      int kg = ks * 4 + (lane >> 4);
      bf16x8 a[4], b[4];
      #pragma unroll
      for (int f = 0; f < 4; ++f){
        int row = wm * 64 + f * 16 + (lane & 15);
        a[f] = *(const bf16x8*)(A + row * 128 + ((kg ^ (row & 7)) << 4));
      }
      #pragma unroll
      for (int f = 0; f < 4; ++f){
        int row = wn * 64 + f * 16 + (lane & 15);
        b[f] = *(const bf16x8*)(B + row * 128 + ((kg ^ (row & 7)) << 4));
      }
      #pragma unroll
      for (int fm = 0; fm < 4; ++fm)
        #pragma unroll
        for (int fn = 0; fn < 4; ++fn)
          acc[fm][fn] = __builtin_amdgcn_mfma_f32_16x16x32_bf16(a[fm], b[fn], acc[fm][fn], 0, 0, 0);
    }
    buf ^= 1;
  }

  #pragma unroll
  for (int fm = 0; fm < 4; ++fm){
    #pragma unroll
    for (int j = 0; j < 4; ++j){
      int row = wm * 64 + fm * 16 + (lane >> 4) * 4 + j;
      int gr = m0 + row;
      if (gr < M){
        #pragma unroll
        for (int fn = 0; fn < 4; ++fn){
          int col = n0 + wn * 64 + fn * 16 + (lane & 15);
          float v = acc[fm][fn][j] + bias[col];
          v = 0.5f * v * (1.0f + erff(v * 0.70710678118654752f));
          hout[(size_t)gr * F_DIM + col] = f2bf(v);
        }
      }
    }
  }
}

// ---------------- grouped GEMM2: out += wgt * (H @ W2 + b2) ----------------
__global__ __launch_bounds__(256, 2) void moe_gemm2(
    const unsigned short* __restrict__ h_rout,
    const unsigned short* __restrict__ h_sh,
    const unsigned short* __restrict__ rw2T,   // [E][H][F]
    const unsigned short* __restrict__ sw2T,   // [2][H][F]
    const float* __restrict__ rb2, const float* __restrict__ sb2,
    const int* __restrict__ counts, const int* __restrict__ offs,
    const int* __restrict__ rows, const float* __restrict__ roww,
    float* __restrict__ out){
  constexpr int K  = F_DIM;   // 2048
  constexpr int NK = K / 64;  // 32
  int job = blockIdx.z;
  int M; const unsigned short* aseg; const unsigned short* wT; const float* bias;
  const int* rmap; const float* rwt;
  if (job < N_EXP){
    M = counts[job];
    int base = offs[job];
    aseg = h_rout + (size_t)base * F_DIM;
    rmap = rows + base; rwt = roww + base;
    wT = rw2T + (size_t)job * H_DIM * F_DIM;
    bias = rb2 + job * H_DIM;
  } else {
    int s = job - N_EXP; M = T_TOK;
    aseg = h_sh + (size_t)s * T_TOK * F_DIM;
    rmap = nullptr; rwt = nullptr;
    wT = sw2T + (size_t)s * H_DIM * F_DIM;
    bias = sb2 + s * H_DIM;
  }
  int m0 = blockIdx.y * 128;
  if (m0 >= M) return;
  int n0 = blockIdx.x * 128;

  __shared__ char smem[65536];
  int tid = threadIdx.x;
  int wave = tid >> 6, lane = tid & 63;
  int wm = wave >> 1, wn = wave & 1;

  const unsigned short* asrc[4];
  const unsigned short* bsrc[4];
  int srow = tid >> 3;
  int slot = tid & 7;
  #pragma unroll
  for (int r = 0; r < 4; ++r){
    int row = r * 32 + srow;
    int gr = m0 + row; if (gr > M - 1) gr = M - 1;
    asrc[r] = aseg + (size_t)gr * K + ((slot ^ (row & 7)) << 3);
    bsrc[r] = wT + (size_t)(n0 + row) * K + ((slot ^ (row & 7)) << 3);
  }

  f32x4 acc[4][4];
  #pragma unroll
  for (int i = 0; i < 4; ++i)
    #pragma unroll
    for (int j = 0; j < 4; ++j) acc[i][j] = (f32x4)0.f;

  auto stage = [&](int buf, int k0){
    char* base = smem + buf * 32768;
    #pragma unroll
    for (int r = 0; r < 4; ++r) GLD16(asrc[r] + k0, base + r * 4096 + wave * 1024);
    #pragma unroll
    for (int r = 0; r < 4; ++r) GLD16(bsrc[r] + k0, base + 16384 + r * 4096 + wave * 1024);
  };

  stage(0, 0);
  int buf = 0;
  for (int kt = 0; kt < NK; ++kt){
    __syncthreads();
    if (kt + 1 < NK) stage(buf ^ 1, (kt + 1) * 64);
    const char* A = smem + buf * 32768;
    const char* B = A + 16384;
    #pragma unroll
    for (int ks = 0; ks < 2; ++ks){
      int kg = ks * 4 + (lane >> 4);
      bf16x8 a[4], b[4];
      #pragma unroll
      for (int f = 0; f < 4; ++f){
        int row = wm * 64 + f * 16 + (lane & 15);
        a[f] = *(const bf16x8*)(A + row * 128 + ((kg ^ (row & 7)) << 4));
      }
      #pragma unroll
      for (int f = 0; f < 4; ++f){
        int row = wn * 64 + f * 16 + (lane & 15);
        b[f] = *(const bf16x8*)(B + row * 128 + ((kg ^ (row & 7)) << 4));
      }
      #pragma unroll
      for (int fm = 0; fm < 4; ++fm)
        #pragma unroll
        for (int fn = 0; fn < 4; ++fn)
          acc[fm][fn] = __builtin_amdgcn_mfma_f32_16x16x32_bf16(a[fm], b[fn], acc[fm][fn], 0, 0, 0);
    }
    buf ^= 1;
  }

  #pragma unroll
  for (int fm = 0; fm < 4; ++fm){
    #pragma unroll
    for (int j = 0; j < 4; ++j){
      int row = wm * 64 + fm * 16 + (lane >> 4) * 4 + j;
      int gr = m0 + row;
      if (gr < M){
        int tok; float coef;
        if (rmap){ tok = rmap[gr]; coef = rwt[gr]; }
        else     { tok = gr;       coef = 1.0f / N_SH; }
        #pragma unroll
        for (int fn = 0; fn < 4; ++fn){
          int col = n0 + wn * 64 + fn * 16 + (lane & 15);
          float v = (acc[fm][fn][j] + bias[col]) * coef;
          atomicAdd(&out[(size_t)tok * H_DIM + col], v);
        }
      }
    }
  }
}

// ---------------- host launcher ----------------
extern "C" void kernel_launch(void* const* d_in, const int* in_sizes, int n_in,
                              void* d_out, int out_size, void* d_ws, size_t ws_size,
                              hipStream_t stream){
  const float* x   = (const float*)d_in[0];
  const float* gw  = (const float*)d_in[1];
  const float* rw1 = (const float*)d_in[2];
  const float* rb1 = (const float*)d_in[3];
  const float* rw2 = (const float*)d_in[4];
  const float* rb2 = (const float*)d_in[5];
  const float* sw1 = (const float*)d_in[6];
  const float* sb1 = (const float*)d_in[7];
  const float* sw2 = (const float*)d_in[8];
  const float* sb2 = (const float*)d_in[9];
  float* out = (float*)d_out;

  char* ws = (char*)d_ws;
  size_t off = 0;
  auto alloc = [&](size_t b){ size_t r = off; off += (b + 255) & ~(size_t)255; return r; };
  unsigned short* xb     = (unsigned short*)(ws + alloc((size_t)T_TOK * H_DIM * 2));
  unsigned short* rw1T   = (unsigned short*)(ws + alloc((size_t)N_EXP * H_DIM * F_DIM * 2));
  unsigned short* rw2T   = (unsigned short*)(ws + alloc((size_t)N_EXP * H_DIM * F_DIM * 2));
  unsigned short* sw1T   = (unsigned short*)(ws + alloc((size_t)N_SH * H_DIM * F_DIM * 2));
  unsigned short* sw2T   = (unsigned short*)(ws + alloc((size_t)N_SH * H_DIM * F_DIM * 2));
  unsigned short* h_rout = (unsigned short*)(ws + alloc((size_t)T_TOK * TOPK * F_DIM * 2));
  unsigned short* h_sh   = (unsigned short*)(ws + alloc((size_t)N_SH * T_TOK * F_DIM * 2));
  int*   counts = (int*)(ws + alloc(64));
  int*   offs   = (int*)(ws + alloc(64));
  int*   cursor = (int*)(ws + alloc(64));
  int*   tki    = (int*)(ws + alloc((size_t)T_TOK * TOPK * 4));
  float* tkw    = (float*)(ws + alloc((size_t)T_TOK * TOPK * 4));
  int*   rowsl  = (int*)(ws + alloc((size_t)T_TOK * TOPK * 4));
  float* roww   = (float*)(ws + alloc((size_t)T_TOK * TOPK * 4));

  hipMemsetAsync(counts, 0, 64, stream);
  hipMemsetAsync(out, 0, (size_t)T_TOK * H_DIM * 4, stream);

  moe_convert_x<<<2048, 256, 0, stream>>>((const float4*)x, (ushort4*)xb);
  moe_transpose<<<dim3(F_DIM / 64, H_DIM / 64, N_EXP), 256, 0, stream>>>(rw1, rw1T, H_DIM, F_DIM);
  moe_transpose<<<dim3(H_DIM / 64, F_DIM / 64, N_EXP), 256, 0, stream>>>(rw2, rw2T, F_DIM, H_DIM);
  moe_transpose<<<dim3(F_DIM / 64, H_DIM / 64, N_SH), 256, 0, stream>>>(sw1, sw1T, H_DIM, F_DIM);
  moe_transpose<<<dim3(H_DIM / 64, F_DIM / 64, N_SH), 256, 0, stream>>>(sw2, sw2T, F_DIM, H_DIM);

  moe_gate<<<T_TOK, 64, 0, stream>>>(x, gw, tki, tkw, counts);
  moe_offsets<<<1, 64, 0, stream>>>(counts, offs, cursor);
  moe_build_rows<<<T_TOK / 256, 256, 0, stream>>>(tki, tkw, cursor, rowsl, roww);

  moe_gemm1<<<dim3(F_DIM / 128, T_TOK / 128, N_EXP + N_SH), 256, 0, stream>>>(
      xb, rw1T, sw1T, rb1, sb1, counts, offs, rowsl, h_rout, h_sh);
  moe_gemm2<<<dim3(H_DIM / 128, T_TOK / 128, N_EXP + N_SH), 256, 0, stream>>>(
      h_rout, h_sh, rw2T, sw2T, rb2, sb2, counts, offs, rowsl, roww, out);
}

// Round 4
// 582.320 us; speedup vs baseline: 1.2085x; 1.2085x over previous
//
#include <hip/hip_runtime.h>

#define T_TOK 4096
#define H_DIM 512
#define F_DIM 2048
#define N_EXP 16
#define N_SH  2
#define TOPK  4

typedef __attribute__((ext_vector_type(4))) float f32x4;
typedef __attribute__((ext_vector_type(8))) short bf16x8;

__device__ __forceinline__ unsigned short f2bf(float f){
  union { float f; unsigned u; } a; a.f = f;
  unsigned u = a.u;
  return (unsigned short)((u + 0x7fffu + ((u >> 16) & 1u)) >> 16);
}

#define GLD16(gsrc, ldst) \
  __builtin_amdgcn_global_load_lds((const __attribute__((address_space(1))) unsigned int*)(gsrc), \
                                   (__attribute__((address_space(3))) unsigned int*)(ldst), 16, 0, 0)

// ---------------- convert x: f32 -> bf16 ----------------
__global__ void moe_convert_x(const float4* __restrict__ src, ushort4* __restrict__ dst){
  int i = blockIdx.x * 256 + threadIdx.x;       // T*H/4 = 524288 total
  float4 v = src[i];
  ushort4 o;
  o.x = f2bf(v.x); o.y = f2bf(v.y); o.z = f2bf(v.z); o.w = f2bf(v.w);
  dst[i] = o;
}

// ---------------- transpose + convert: src[R][C] f32 -> dst[C][R] bf16 ----------------
__global__ void moe_transpose(const float* __restrict__ src, unsigned short* __restrict__ dst,
                              int R, int C){
  __shared__ float tile[64][65];
  size_t matoff = (size_t)blockIdx.z * (size_t)R * (size_t)C;
  src += matoff; dst += matoff;
  int c0 = blockIdx.x * 64, r0 = blockIdx.y * 64;
  int t = threadIdx.x;
  #pragma unroll
  for (int i = 0; i < 16; ++i){
    int idx = i * 256 + t; int r = idx >> 6, c = idx & 63;
    tile[r][c] = src[(size_t)(r0 + r) * C + (c0 + c)];
  }
  __syncthreads();
  #pragma unroll
  for (int i = 0; i < 16; ++i){
    int idx = i * 256 + t; int r = idx >> 6, c = idx & 63;
    dst[(size_t)(c0 + r) * R + (r0 + c)] = f2bf(tile[c][r]);
  }
}

// ---------------- gating (fp32, thread-per-token): softmax -> top4 -> softmax(top4) ----------------
// Round-3 rocprof: the wave-per-token fp64 gate was 206 us (VALUBusy 3.8%,
// lane-0-serial fp64 exp). Thread-per-token fp32 with gw staged in LDS.
// (fp32 routing == fp64 routing was verified bit-exact in rounds 1/2.)
__global__ __launch_bounds__(256) void moe_gate(
    const float* __restrict__ x, const float* __restrict__ gw,
    int* __restrict__ tki, float* __restrict__ tkw,
    int* __restrict__ counts){
  __shared__ float gwl[N_EXP * H_DIM];          // 32 KB
  int tid = threadIdx.x;
  #pragma unroll
  for (int i = 0; i < N_EXP * H_DIM / 256; ++i)
    gwl[i * 256 + tid] = gw[i * 256 + tid];
  __syncthreads();

  int t = blockIdx.x * 256 + tid;
  const float4* xr = (const float4*)(x + (size_t)t * H_DIM);
  float acc[N_EXP];
  #pragma unroll
  for (int e = 0; e < N_EXP; ++e) acc[e] = 0.f;
  for (int h4 = 0; h4 < H_DIM / 4; ++h4){
    float4 xv = xr[h4];
    #pragma unroll
    for (int e = 0; e < N_EXP; ++e){
      const float* wrow = &gwl[e * H_DIM + h4 * 4];   // wave-uniform -> LDS broadcast
      acc[e] += xv.x * wrow[0] + xv.y * wrow[1] + xv.z * wrow[2] + xv.w * wrow[3];
    }
  }
  // softmax over 16
  float m = -1e30f;
  #pragma unroll
  for (int e = 0; e < N_EXP; ++e) m = fmaxf(m, acc[e]);
  float Z = 0.f;
  #pragma unroll
  for (int e = 0; e < N_EXP; ++e){ acc[e] = __expf(acc[e] - m); Z += acc[e]; }
  float inv = 1.f / Z;
  #pragma unroll
  for (int e = 0; e < N_EXP; ++e) acc[e] *= inv;
  // top-4, strict > with ascending scan (numpy tie-break: lowest index wins)
  int sel[TOPK]; float sv[TOPK];
  unsigned used = 0;
  #pragma unroll
  for (int k = 0; k < TOPK; ++k){
    int best = 0; float bv = -1.f;
    #pragma unroll
    for (int e = 0; e < N_EXP; ++e)
      if (!((used >> e) & 1u) && acc[e] > bv){ bv = acc[e]; best = e; }
    used |= 1u << best; sel[k] = best; sv[k] = bv;
  }
  // renormalize top-4 (save max BEFORE the exp loop!)
  float m0 = sv[0];
  float Z2 = 0.f;
  #pragma unroll
  for (int k = 0; k < TOPK; ++k){ sv[k] = __expf(sv[k] - m0); Z2 += sv[k]; }
  float i2 = 1.f / Z2;
  #pragma unroll
  for (int k = 0; k < TOPK; ++k){
    tki[t * TOPK + k] = sel[k];
    tkw[t * TOPK + k] = sv[k] * i2;
    atomicAdd(&counts[sel[k]], 1);
  }
}

// ---------------- prefix offsets (1 thread) ----------------
__global__ void moe_offsets(const int* __restrict__ counts, int* __restrict__ offs,
                            int* __restrict__ cursor){
  if (threadIdx.x == 0){
    int a = 0;
    for (int e = 0; e < N_EXP; ++e){ offs[e] = a; cursor[e] = a; a += counts[e]; }
  }
}

// ---------------- build per-expert row lists ----------------
__global__ void moe_build_rows(const int* __restrict__ tki, const float* __restrict__ tkw,
                               int* __restrict__ cursor, int* __restrict__ rows,
                               float* __restrict__ roww){
  int t = blockIdx.x * 256 + threadIdx.x;
  if (t >= T_TOK) return;
  for (int k = 0; k < TOPK; ++k){
    int e = tki[t * TOPK + k];
    int pos = atomicAdd(&cursor[e], 1);
    rows[pos] = t;
    roww[pos] = tkw[t * TOPK + k];
  }
}

// ---------------- grouped GEMM1: h = gelu(X @ W1 + b1), bf16 out ----------------
__global__ __launch_bounds__(256, 2) void moe_gemm1(
    const unsigned short* __restrict__ xb,
    const unsigned short* __restrict__ rw1T,   // [E][F][H]
    const unsigned short* __restrict__ sw1T,   // [2][F][H]
    const float* __restrict__ rb1, const float* __restrict__ sb1,
    const int* __restrict__ counts, const int* __restrict__ offs,
    const int* __restrict__ rows,
    unsigned short* __restrict__ h_rout, unsigned short* __restrict__ h_sh){
  constexpr int K  = H_DIM;   // 512
  constexpr int NK = K / 64;  // 8
  int job = blockIdx.z;
  int M; const int* rmap; const unsigned short* wT; const float* bias; unsigned short* hout;
  if (job < N_EXP){
    M = counts[job];
    int base = offs[job];
    rmap = rows + base;
    wT = rw1T + (size_t)job * F_DIM * H_DIM;
    bias = rb1 + job * F_DIM;
    hout = h_rout + (size_t)base * F_DIM;
  } else {
    int s = job - N_EXP;
    M = T_TOK; rmap = nullptr;
    wT = sw1T + (size_t)s * F_DIM * H_DIM;
    bias = sb1 + s * F_DIM;
    hout = h_sh + (size_t)s * T_TOK * F_DIM;
  }
  int m0 = blockIdx.y * 128;
  if (m0 >= M) return;
  int n0 = blockIdx.x * 128;

  __shared__ char smem[65536];
  int tid = threadIdx.x;
  int wave = tid >> 6, lane = tid & 63;
  int wm = wave >> 1, wn = wave & 1;

  const unsigned short* asrc[4];
  const unsigned short* bsrc[4];
  int srow = tid >> 3;   // 0..31
  int slot = tid & 7;
  #pragma unroll
  for (int r = 0; r < 4; ++r){
    int row = r * 32 + srow;
    int gr = m0 + row; if (gr > M - 1) gr = M - 1;
    int tok = rmap ? rmap[gr] : gr;
    asrc[r] = xb + (size_t)tok * H_DIM + ((slot ^ (row & 7)) << 3);
    bsrc[r] = wT + (size_t)(n0 + row) * K + ((slot ^ (row & 7)) << 3);
  }

  f32x4 acc[4][4];
  #pragma unroll
  for (int i = 0; i < 4; ++i)
    #pragma unroll
    for (int j = 0; j < 4; ++j) acc[i][j] = (f32x4)0.f;

  auto stage = [&](int buf, int k0){
    char* base = smem + buf * 32768;
    #pragma unroll
    for (int r = 0; r < 4; ++r) GLD16(asrc[r] + k0, base + r * 4096 + wave * 1024);
    #pragma unroll
    for (int r = 0; r < 4; ++r) GLD16(bsrc[r] + k0, base + 16384 + r * 4096 + wave * 1024);
  };

  stage(0, 0);
  int buf = 0;
  for (int kt = 0; kt < NK; ++kt){
    __syncthreads();
    if (kt + 1 < NK) stage(buf ^ 1, (kt + 1) * 64);
    const char* A = smem + buf * 32768;
    const char* B = A + 16384;
    #pragma unroll
    for (int ks = 0; ks < 2; ++ks){
      int kg = ks * 4 + (lane >> 4);
      bf16x8 a[4], b[4];
      #pragma unroll
      for (int f = 0; f < 4; ++f){
        int row = wm * 64 + f * 16 + (lane & 15);
        a[f] = *(const bf16x8*)(A + row * 128 + ((kg ^ (row & 7)) << 4));
      }
      #pragma unroll
      for (int f = 0; f < 4; ++f){
        int row = wn * 64 + f * 16 + (lane & 15);
        b[f] = *(const bf16x8*)(B + row * 128 + ((kg ^ (row & 7)) << 4));
      }
      #pragma unroll
      for (int fm = 0; fm < 4; ++fm)
        #pragma unroll
        for (int fn = 0; fn < 4; ++fn)
          acc[fm][fn] = __builtin_amdgcn_mfma_f32_16x16x32_bf16(a[fm], b[fn], acc[fm][fn], 0, 0, 0);
    }
    buf ^= 1;
  }

  #pragma unroll
  for (int fm = 0; fm < 4; ++fm){
    #pragma unroll
    for (int j = 0; j < 4; ++j){
      int row = wm * 64 + fm * 16 + (lane >> 4) * 4 + j;
      int gr = m0 + row;
      if (gr < M){
        #pragma unroll
        for (int fn = 0; fn < 4; ++fn){
          int col = n0 + wn * 64 + fn * 16 + (lane & 15);
          float v = acc[fm][fn][j] + bias[col];
          v = 0.5f * v * (1.0f + erff(v * 0.70710678118654752f));
          hout[(size_t)gr * F_DIM + col] = f2bf(v);
        }
      }
    }
  }
}

// ---------------- grouped GEMM2: out += wgt * (H @ W2 + b2) ----------------
__global__ __launch_bounds__(256, 2) void moe_gemm2(
    const unsigned short* __restrict__ h_rout,
    const unsigned short* __restrict__ h_sh,
    const unsigned short* __restrict__ rw2T,   // [E][H][F]
    const unsigned short* __restrict__ sw2T,   // [2][H][F]
    const float* __restrict__ rb2, const float* __restrict__ sb2,
    const int* __restrict__ counts, const int* __restrict__ offs,
    const int* __restrict__ rows, const float* __restrict__ roww,
    float* __restrict__ out){
  constexpr int K  = F_DIM;   // 2048
  constexpr int NK = K / 64;  // 32
  int job = blockIdx.z;
  int M; const unsigned short* aseg; const unsigned short* wT; const float* bias;
  const int* rmap; const float* rwt;
  if (job < N_EXP){
    M = counts[job];
    int base = offs[job];
    aseg = h_rout + (size_t)base * F_DIM;
    rmap = rows + base; rwt = roww + base;
    wT = rw2T + (size_t)job * H_DIM * F_DIM;
    bias = rb2 + job * H_DIM;
  } else {
    int s = job - N_EXP; M = T_TOK;
    aseg = h_sh + (size_t)s * T_TOK * F_DIM;
    rmap = nullptr; rwt = nullptr;
    wT = sw2T + (size_t)s * H_DIM * F_DIM;
    bias = sb2 + s * H_DIM;
  }
  int m0 = blockIdx.y * 128;
  if (m0 >= M) return;
  int n0 = blockIdx.x * 128;

  __shared__ char smem[65536];
  int tid = threadIdx.x;
  int wave = tid >> 6, lane = tid & 63;
  int wm = wave >> 1, wn = wave & 1;

  const unsigned short* asrc[4];
  const unsigned short* bsrc[4];
  int srow = tid >> 3;
  int slot = tid & 7;
  #pragma unroll
  for (int r = 0; r < 4; ++r){
    int row = r * 32 + srow;
    int gr = m0 + row; if (gr > M - 1) gr = M - 1;
    asrc[r] = aseg + (size_t)gr * K + ((slot ^ (row & 7)) << 3);
    bsrc[r] = wT + (size_t)(n0 + row) * K + ((slot ^ (row & 7)) << 3);
  }

  f32x4 acc[4][4];
  #pragma unroll
  for (int i = 0; i < 4; ++i)
    #pragma unroll
    for (int j = 0; j < 4; ++j) acc[i][j] = (f32x4)0.f;

  auto stage = [&](int buf, int k0){
    char* base = smem + buf * 32768;
    #pragma unroll
    for (int r = 0; r < 4; ++r) GLD16(asrc[r] + k0, base + r * 4096 + wave * 1024);
    #pragma unroll
    for (int r = 0; r < 4; ++r) GLD16(bsrc[r] + k0, base + 16384 + r * 4096 + wave * 1024);
  };

  stage(0, 0);
  int buf = 0;
  for (int kt = 0; kt < NK; ++kt){
    __syncthreads();
    if (kt + 1 < NK) stage(buf ^ 1, (kt + 1) * 64);
    const char* A = smem + buf * 32768;
    const char* B = A + 16384;
    #pragma unroll
    for (int ks = 0; ks < 2; ++ks){
      int kg = ks * 4 + (lane >> 4);
      bf16x8 a[4], b[4];
      #pragma unroll
      for (int f = 0; f < 4; ++f){
        int row = wm * 64 + f * 16 + (lane & 15);
        a[f] = *(const bf16x8*)(A + row * 128 + ((kg ^ (row & 7)) << 4));
      }
      #pragma unroll
      for (int f = 0; f < 4; ++f){
        int row = wn * 64 + f * 16 + (lane & 15);
        b[f] = *(const bf16x8*)(B + row * 128 + ((kg ^ (row & 7)) << 4));
      }
      #pragma unroll
      for (int fm = 0; fm < 4; ++fm)
        #pragma unroll
        for (int fn = 0; fn < 4; ++fn)
          acc[fm][fn] = __builtin_amdgcn_mfma_f32_16x16x32_bf16(a[fm], b[fn], acc[fm][fn], 0, 0, 0);
    }
    buf ^= 1;
  }

  #pragma unroll
  for (int fm = 0; fm < 4; ++fm){
    #pragma unroll
    for (int j = 0; j < 4; ++j){
      int row = wm * 64 + fm * 16 + (lane >> 4) * 4 + j;
      int gr = m0 + row;
      if (gr < M){
        int tok; float coef;
        if (rmap){ tok = rmap[gr]; coef = rwt[gr]; }
        else     { tok = gr;       coef = 1.0f / N_SH; }
        #pragma unroll
        for (int fn = 0; fn < 4; ++fn){
          int col = n0 + wn * 64 + fn * 16 + (lane & 15);
          float v = (acc[fm][fn][j] + bias[col]) * coef;
          atomicAdd(&out[(size_t)tok * H_DIM + col], v);
        }
      }
    }
  }
}

// ---------------- host launcher ----------------
extern "C" void kernel_launch(void* const* d_in, const int* in_sizes, int n_in,
                              void* d_out, int out_size, void* d_ws, size_t ws_size,
                              hipStream_t stream){
  const float* x   = (const float*)d_in[0];
  const float* gw  = (const float*)d_in[1];
  const float* rw1 = (const float*)d_in[2];
  const float* rb1 = (const float*)d_in[3];
  const float* rw2 = (const float*)d_in[4];
  const float* rb2 = (const float*)d_in[5];
  const float* sw1 = (const float*)d_in[6];
  const float* sb1 = (const float*)d_in[7];
  const float* sw2 = (const float*)d_in[8];
  const float* sb2 = (const float*)d_in[9];
  float* out = (float*)d_out;

  char* ws = (char*)d_ws;
  size_t off = 0;
  auto alloc = [&](size_t b){ size_t r = off; off += (b + 255) & ~(size_t)255; return r; };
  unsigned short* xb     = (unsigned short*)(ws + alloc((size_t)T_TOK * H_DIM * 2));
  unsigned short* rw1T   = (unsigned short*)(ws + alloc((size_t)N_EXP * H_DIM * F_DIM * 2));
  unsigned short* rw2T   = (unsigned short*)(ws + alloc((size_t)N_EXP * H_DIM * F_DIM * 2));
  unsigned short* sw1T   = (unsigned short*)(ws + alloc((size_t)N_SH * H_DIM * F_DIM * 2));
  unsigned short* sw2T   = (unsigned short*)(ws + alloc((size_t)N_SH * H_DIM * F_DIM * 2));
  unsigned short* h_rout = (unsigned short*)(ws + alloc((size_t)T_TOK * TOPK * F_DIM * 2));
  unsigned short* h_sh   = (unsigned short*)(ws + alloc((size_t)N_SH * T_TOK * F_DIM * 2));
  int*   counts = (int*)(ws + alloc(64));
  int*   offs   = (int*)(ws + alloc(64));
  int*   cursor = (int*)(ws + alloc(64));
  int*   tki    = (int*)(ws + alloc((size_t)T_TOK * TOPK * 4));
  float* tkw    = (float*)(ws + alloc((size_t)T_TOK * TOPK * 4));
  int*   rowsl  = (int*)(ws + alloc((size_t)T_TOK * TOPK * 4));
  float* roww   = (float*)(ws + alloc((size_t)T_TOK * TOPK * 4));

  hipMemsetAsync(counts, 0, 64, stream);
  hipMemsetAsync(out, 0, (size_t)T_TOK * H_DIM * 4, stream);

  moe_convert_x<<<2048, 256, 0, stream>>>((const float4*)x, (ushort4*)xb);
  moe_transpose<<<dim3(F_DIM / 64, H_DIM / 64, N_EXP), 256, 0, stream>>>(rw1, rw1T, H_DIM, F_DIM);
  moe_transpose<<<dim3(H_DIM / 64, F_DIM / 64, N_EXP), 256, 0, stream>>>(rw2, rw2T, F_DIM, H_DIM);
  moe_transpose<<<dim3(F_DIM / 64, H_DIM / 64, N_SH), 256, 0, stream>>>(sw1, sw1T, H_DIM, F_DIM);
  moe_transpose<<<dim3(H_DIM / 64, F_DIM / 64, N_SH), 256, 0, stream>>>(sw2, sw2T, F_DIM, H_DIM);

  moe_gate<<<T_TOK / 256, 256, 0, stream>>>(x, gw, tki, tkw, counts);
  moe_offsets<<<1, 64, 0, stream>>>(counts, offs, cursor);
  moe_build_rows<<<T_TOK / 256, 256, 0, stream>>>(tki, tkw, cursor, rowsl, roww);

  moe_gemm1<<<dim3(F_DIM / 128, T_TOK / 128, N_EXP + N_SH), 256, 0, stream>>>(
      xb, rw1T, sw1T, rb1, sb1, counts, offs, rowsl, h_rout, h_sh);
  moe_gemm2<<<dim3(H_DIM / 128, T_TOK / 128, N_EXP + N_SH), 256, 0, stream>>>(
      h_rout, h_sh, rw2T, sw2T, rb2, sb2, counts, offs, rowsl, roww, out);
}

// Round 5
// 542.302 us; speedup vs baseline: 1.2977x; 1.0738x over previous
//
#include <hip/hip_runtime.h>

#define T_TOK 4096
#define H_DIM 512
#define F_DIM 2048
#define N_EXP 16
#define N_SH  2
#define TOPK  4

typedef __attribute__((ext_vector_type(4))) float f32x4;
typedef __attribute__((ext_vector_type(8))) short bf16x8;

__device__ __forceinline__ unsigned short f2bf(float f){
  union { float f; unsigned u; } a; a.f = f;
  unsigned u = a.u;
  return (unsigned short)((u + 0x7fffu + ((u >> 16) & 1u)) >> 16);
}

// exp-based tanh-GELU: |err| < ~1e-3 abs, far under the bf16-h quantization.
// (round-4 rocprof: erff epilogue ~1600 VALU cyc/wave > the 1230-cyc MFMA loop)
__device__ __forceinline__ float fast_gelu(float v){
  float u = 0.7978845608f * (v + 0.044715f * v * v * v);
  u = fminf(fmaxf(u, -15.f), 15.f);
  float e = __expf(2.f * u);
  float th = (e - 1.f) * __builtin_amdgcn_rcpf(e + 1.f);
  return 0.5f * v * (1.f + th);
}

#define GLD16(gsrc, ldst) \
  __builtin_amdgcn_global_load_lds((const __attribute__((address_space(1))) unsigned int*)(gsrc), \
                                   (__attribute__((address_space(3))) unsigned int*)(ldst), 16, 0, 0)

// ---------------- transpose + convert: src[R][C] f32 -> dst[C][R] bf16 (routed+shared fused) ----------------
__global__ void moe_transpose2(const float* __restrict__ s0, const float* __restrict__ s1,
                               unsigned short* __restrict__ d0, unsigned short* __restrict__ d1,
                               int R, int C){
  __shared__ float tile[64][65];
  int z = blockIdx.z;
  size_t per = (size_t)R * C;
  const float* src      = (z < N_EXP) ? s0 + (size_t)z * per : s1 + (size_t)(z - N_EXP) * per;
  unsigned short* dst   = (z < N_EXP) ? d0 + (size_t)z * per : d1 + (size_t)(z - N_EXP) * per;
  int c0 = blockIdx.x * 64, r0 = blockIdx.y * 64;
  int t = threadIdx.x;
  #pragma unroll
  for (int i = 0; i < 16; ++i){
    int idx = i * 256 + t; int r = idx >> 6, c = idx & 63;
    tile[r][c] = src[(size_t)(r0 + r) * C + (c0 + c)];
  }
  __syncthreads();
  #pragma unroll
  for (int i = 0; i < 16; ++i){
    int idx = i * 256 + t; int r = idx >> 6, c = idx & 63;
    dst[(size_t)(c0 + r) * R + (r0 + c)] = f2bf(tile[c][r]);
  }
}

// ---------------- gating (fp32, thread-per-token) + x->bf16 conversion fused ----------------
__global__ __launch_bounds__(256) void moe_gate(
    const float* __restrict__ x, const float* __restrict__ gw,
    unsigned short* __restrict__ xb,
    int* __restrict__ tki, float* __restrict__ tkw,
    int* __restrict__ counts){
  __shared__ float gwl[N_EXP * H_DIM];          // 32 KB
  int tid = threadIdx.x;
  #pragma unroll
  for (int i = 0; i < N_EXP * H_DIM / 256; ++i)
    gwl[i * 256 + tid] = gw[i * 256 + tid];
  __syncthreads();

  int t = blockIdx.x * 256 + tid;
  const float4* xr = (const float4*)(x + (size_t)t * H_DIM);
  ushort4* xw = (ushort4*)(xb + (size_t)t * H_DIM);
  float acc[N_EXP];
  #pragma unroll
  for (int e = 0; e < N_EXP; ++e) acc[e] = 0.f;
  for (int h4 = 0; h4 < H_DIM / 4; ++h4){
    float4 xv = xr[h4];
    ushort4 o; o.x = f2bf(xv.x); o.y = f2bf(xv.y); o.z = f2bf(xv.z); o.w = f2bf(xv.w);
    xw[h4] = o;
    #pragma unroll
    for (int e = 0; e < N_EXP; ++e){
      const float* wrow = &gwl[e * H_DIM + h4 * 4];   // wave-uniform -> LDS broadcast
      acc[e] += xv.x * wrow[0] + xv.y * wrow[1] + xv.z * wrow[2] + xv.w * wrow[3];
    }
  }
  // softmax over 16
  float m = -1e30f;
  #pragma unroll
  for (int e = 0; e < N_EXP; ++e) m = fmaxf(m, acc[e]);
  float Z = 0.f;
  #pragma unroll
  for (int e = 0; e < N_EXP; ++e){ acc[e] = __expf(acc[e] - m); Z += acc[e]; }
  float inv = 1.f / Z;
  #pragma unroll
  for (int e = 0; e < N_EXP; ++e) acc[e] *= inv;
  // top-4, strict > with ascending scan (numpy tie-break: lowest index wins)
  int sel[TOPK]; float sv[TOPK];
  unsigned used = 0;
  #pragma unroll
  for (int k = 0; k < TOPK; ++k){
    int best = 0; float bv = -1.f;
    #pragma unroll
    for (int e = 0; e < N_EXP; ++e)
      if (!((used >> e) & 1u) && acc[e] > bv){ bv = acc[e]; best = e; }
    used |= 1u << best; sel[k] = best; sv[k] = bv;
  }
  // renormalize top-4 (save max BEFORE the exp loop!)
  float m0 = sv[0];
  float Z2 = 0.f;
  #pragma unroll
  for (int k = 0; k < TOPK; ++k){ sv[k] = __expf(sv[k] - m0); Z2 += sv[k]; }
  float i2 = 1.f / Z2;
  #pragma unroll
  for (int k = 0; k < TOPK; ++k){
    tki[t * TOPK + k] = sel[k];
    tkw[t * TOPK + k] = sv[k] * i2;
    atomicAdd(&counts[sel[k]], 1);
  }
}

// ---------------- prefix offsets (1 thread) ----------------
__global__ void moe_offsets(const int* __restrict__ counts, int* __restrict__ offs,
                            int* __restrict__ cursor){
  if (threadIdx.x == 0){
    int a = 0;
    for (int e = 0; e < N_EXP; ++e){ offs[e] = a; cursor[e] = a; a += counts[e]; }
  }
}

// ---------------- build per-expert row lists ----------------
__global__ void moe_build_rows(const int* __restrict__ tki, const float* __restrict__ tkw,
                               int* __restrict__ cursor, int* __restrict__ rows,
                               float* __restrict__ roww){
  int t = blockIdx.x * 256 + threadIdx.x;
  if (t >= T_TOK) return;
  for (int k = 0; k < TOPK; ++k){
    int e = tki[t * TOPK + k];
    int pos = atomicAdd(&cursor[e], 1);
    rows[pos] = t;
    roww[pos] = tkw[t * TOPK + k];
  }
}

// ---------------- grouped GEMM1: h = gelu(X @ W1 + b1), bf16 out ----------------
// Single 32KB LDS buffer, 2-barrier K-loop (m97 structure): occupancy over dbuf.
__global__ __launch_bounds__(256, 4) void moe_gemm1(
    const unsigned short* __restrict__ xb,
    const unsigned short* __restrict__ rw1T,   // [E][F][H]
    const unsigned short* __restrict__ sw1T,   // [2][F][H]
    const float* __restrict__ rb1, const float* __restrict__ sb1,
    const int* __restrict__ counts, const int* __restrict__ offs,
    const int* __restrict__ rows,
    unsigned short* __restrict__ h_rout, unsigned short* __restrict__ h_sh){
  constexpr int K  = H_DIM;   // 512
  constexpr int NK = K / 64;  // 8
  int job = blockIdx.z;
  int M; const int* rmap; const unsigned short* wT; const float* bias; unsigned short* hout;
  if (job < N_EXP){
    M = counts[job];
    int base = offs[job];
    rmap = rows + base;
    wT = rw1T + (size_t)job * F_DIM * H_DIM;
    bias = rb1 + job * F_DIM;
    hout = h_rout + (size_t)base * F_DIM;
  } else {
    int s = job - N_EXP;
    M = T_TOK; rmap = nullptr;
    wT = sw1T + (size_t)s * F_DIM * H_DIM;
    bias = sb1 + s * F_DIM;
    hout = h_sh + (size_t)s * T_TOK * F_DIM;
  }
  int m0 = blockIdx.y * 128;
  if (m0 >= M) return;
  int n0 = blockIdx.x * 128;

  __shared__ char smem[32768];
  int tid = threadIdx.x;
  int wave = tid >> 6, lane = tid & 63;
  int wm = wave >> 1, wn = wave & 1;

  const unsigned short* asrc[4];
  const unsigned short* bsrc[4];
  int srow = tid >> 3;   // 0..31
  int slot = tid & 7;
  #pragma unroll
  for (int r = 0; r < 4; ++r){
    int row = r * 32 + srow;
    int gr = m0 + row; if (gr > M - 1) gr = M - 1;
    int tok = rmap ? rmap[gr] : gr;
    asrc[r] = xb + (size_t)tok * H_DIM + ((slot ^ (row & 7)) << 3);
    bsrc[r] = wT + (size_t)(n0 + row) * K + ((slot ^ (row & 7)) << 3);
  }

  f32x4 acc[4][4];
  #pragma unroll
  for (int i = 0; i < 4; ++i)
    #pragma unroll
    for (int j = 0; j < 4; ++j) acc[i][j] = (f32x4)0.f;

  auto stage = [&](int k0){
    #pragma unroll
    for (int r = 0; r < 4; ++r) GLD16(asrc[r] + k0, smem + r * 4096 + wave * 1024);
    #pragma unroll
    for (int r = 0; r < 4; ++r) GLD16(bsrc[r] + k0, smem + 16384 + r * 4096 + wave * 1024);
  };

  for (int kt = 0; kt < NK; ++kt){
    if (kt) __syncthreads();            // all waves done reading previous tile
    stage(kt * 64);
    __syncthreads();                    // vmcnt(0) drained per-wave, then barrier
    const char* A = smem;
    const char* B = A + 16384;
    #pragma unroll
    for (int ks = 0; ks < 2; ++ks){
      int kg = ks * 4 + (lane >> 4);
      bf16x8 a[4], b[4];
      #pragma unroll
      for (int f = 0; f < 4; ++f){
        int row = wm * 64 + f * 16 + (lane & 15);
        a[f] = *(const bf16x8*)(A + row * 128 + ((kg ^ (row & 7)) << 4));
      }
      #pragma unroll
      for (int f = 0; f < 4; ++f){
        int row = wn * 64 + f * 16 + (lane & 15);
        b[f] = *(const bf16x8*)(B + row * 128 + ((kg ^ (row & 7)) << 4));
      }
      #pragma unroll
      for (int fm = 0; fm < 4; ++fm)
        #pragma unroll
        for (int fn = 0; fn < 4; ++fn)
          acc[fm][fn] = __builtin_amdgcn_mfma_f32_16x16x32_bf16(a[fm], b[fn], acc[fm][fn], 0, 0, 0);
    }
  }

  #pragma unroll
  for (int fm = 0; fm < 4; ++fm){
    #pragma unroll
    for (int j = 0; j < 4; ++j){
      int row = wm * 64 + fm * 16 + (lane >> 4) * 4 + j;
      int gr = m0 + row;
      if (gr < M){
        #pragma unroll
        for (int fn = 0; fn < 4; ++fn){
          int col = n0 + wn * 64 + fn * 16 + (lane & 15);
          float v = acc[fm][fn][j] + bias[col];
          hout[(size_t)gr * F_DIM + col] = f2bf(fast_gelu(v));
        }
      }
    }
  }
}

// ---------------- grouped GEMM2: out += wgt * (H @ W2 + b2) ----------------
__global__ __launch_bounds__(256, 4) void moe_gemm2(
    const unsigned short* __restrict__ h_rout,
    const unsigned short* __restrict__ h_sh,
    const unsigned short* __restrict__ rw2T,   // [E][H][F]
    const unsigned short* __restrict__ sw2T,   // [2][H][F]
    const float* __restrict__ rb2, const float* __restrict__ sb2,
    const int* __restrict__ counts, const int* __restrict__ offs,
    const int* __restrict__ rows, const float* __restrict__ roww,
    float* __restrict__ out){
  constexpr int K  = F_DIM;   // 2048
  constexpr int NK = K / 64;  // 32
  int job = blockIdx.z;
  int M; const unsigned short* aseg; const unsigned short* wT; const float* bias;
  const int* rmap; const float* rwt;
  if (job < N_EXP){
    M = counts[job];
    int base = offs[job];
    aseg = h_rout + (size_t)base * F_DIM;
    rmap = rows + base; rwt = roww + base;
    wT = rw2T + (size_t)job * H_DIM * F_DIM;
    bias = rb2 + job * H_DIM;
  } else {
    int s = job - N_EXP; M = T_TOK;
    aseg = h_sh + (size_t)s * T_TOK * F_DIM;
    rmap = nullptr; rwt = nullptr;
    wT = sw2T + (size_t)s * H_DIM * F_DIM;
    bias = sb2 + s * H_DIM;
  }
  int m0 = blockIdx.y * 128;
  if (m0 >= M) return;
  int n0 = blockIdx.x * 128;

  __shared__ char smem[32768];
  int tid = threadIdx.x;
  int wave = tid >> 6, lane = tid & 63;
  int wm = wave >> 1, wn = wave & 1;

  const unsigned short* asrc[4];
  const unsigned short* bsrc[4];
  int srow = tid >> 3;
  int slot = tid & 7;
  #pragma unroll
  for (int r = 0; r < 4; ++r){
    int row = r * 32 + srow;
    int gr = m0 + row; if (gr > M - 1) gr = M - 1;
    asrc[r] = aseg + (size_t)gr * K + ((slot ^ (row & 7)) << 3);
    bsrc[r] = wT + (size_t)(n0 + row) * K + ((slot ^ (row & 7)) << 3);
  }

  f32x4 acc[4][4];
  #pragma unroll
  for (int i = 0; i < 4; ++i)
    #pragma unroll
    for (int j = 0; j < 4; ++j) acc[i][j] = (f32x4)0.f;

  auto stage = [&](int k0){
    #pragma unroll
    for (int r = 0; r < 4; ++r) GLD16(asrc[r] + k0, smem + r * 4096 + wave * 1024);
    #pragma unroll
    for (int r = 0; r < 4; ++r) GLD16(bsrc[r] + k0, smem + 16384 + r * 4096 + wave * 1024);
  };

  for (int kt = 0; kt < NK; ++kt){
    if (kt) __syncthreads();
    stage(kt * 64);
    __syncthreads();
    const char* A = smem;
    const char* B = A + 16384;
    #pragma unroll
    for (int ks = 0; ks < 2; ++ks){
      int kg = ks * 4 + (lane >> 4);
      bf16x8 a[4], b[4];
      #pragma unroll
      for (int f = 0; f < 4; ++f){
        int row = wm * 64 + f * 16 + (lane & 15);
        a[f] = *(const bf16x8*)(A + row * 128 + ((kg ^ (row & 7)) << 4));
      }
      #pragma unroll
      for (int f = 0; f < 4; ++f){
        int row = wn * 64 + f * 16 + (lane & 15);
        b[f] = *(const bf16x8*)(B + row * 128 + ((kg ^ (row & 7)) << 4));
      }
      #pragma unroll
      for (int fm = 0; fm < 4; ++fm)
        #pragma unroll
        for (int fn = 0; fn < 4; ++fn)
          acc[fm][fn] = __builtin_amdgcn_mfma_f32_16x16x32_bf16(a[fm], b[fn], acc[fm][fn], 0, 0, 0);
    }
  }

  #pragma unroll
  for (int fm = 0; fm < 4; ++fm){
    #pragma unroll
    for (int j = 0; j < 4; ++j){
      int row = wm * 64 + fm * 16 + (lane >> 4) * 4 + j;
      int gr = m0 + row;
      if (gr < M){
        int tok; float coef;
        if (rmap){ tok = rmap[gr]; coef = rwt[gr]; }
        else     { tok = gr;       coef = 1.0f / N_SH; }
        #pragma unroll
        for (int fn = 0; fn < 4; ++fn){
          int col = n0 + wn * 64 + fn * 16 + (lane & 15);
          float v = (acc[fm][fn][j] + bias[col]) * coef;
          atomicAdd(&out[(size_t)tok * H_DIM + col], v);
        }
      }
    }
  }
}

// ---------------- host launcher ----------------
extern "C" void kernel_launch(void* const* d_in, const int* in_sizes, int n_in,
                              void* d_out, int out_size, void* d_ws, size_t ws_size,
                              hipStream_t stream){
  const float* x   = (const float*)d_in[0];
  const float* gw  = (const float*)d_in[1];
  const float* rw1 = (const float*)d_in[2];
  const float* rb1 = (const float*)d_in[3];
  const float* rw2 = (const float*)d_in[4];
  const float* rb2 = (const float*)d_in[5];
  const float* sw1 = (const float*)d_in[6];
  const float* sb1 = (const float*)d_in[7];
  const float* sw2 = (const float*)d_in[8];
  const float* sb2 = (const float*)d_in[9];
  float* out = (float*)d_out;

  char* ws = (char*)d_ws;
  size_t off = 0;
  auto alloc = [&](size_t b){ size_t r = off; off += (b + 255) & ~(size_t)255; return r; };
  unsigned short* xb     = (unsigned short*)(ws + alloc((size_t)T_TOK * H_DIM * 2));
  unsigned short* rw1T   = (unsigned short*)(ws + alloc((size_t)N_EXP * H_DIM * F_DIM * 2));
  unsigned short* rw2T   = (unsigned short*)(ws + alloc((size_t)N_EXP * H_DIM * F_DIM * 2));
  unsigned short* sw1T   = (unsigned short*)(ws + alloc((size_t)N_SH * H_DIM * F_DIM * 2));
  unsigned short* sw2T   = (unsigned short*)(ws + alloc((size_t)N_SH * H_DIM * F_DIM * 2));
  unsigned short* h_rout = (unsigned short*)(ws + alloc((size_t)T_TOK * TOPK * F_DIM * 2));
  unsigned short* h_sh   = (unsigned short*)(ws + alloc((size_t)N_SH * T_TOK * F_DIM * 2));
  int*   counts = (int*)(ws + alloc(64));
  int*   offs   = (int*)(ws + alloc(64));
  int*   cursor = (int*)(ws + alloc(64));
  int*   tki    = (int*)(ws + alloc((size_t)T_TOK * TOPK * 4));
  float* tkw    = (float*)(ws + alloc((size_t)T_TOK * TOPK * 4));
  int*   rowsl  = (int*)(ws + alloc((size_t)T_TOK * TOPK * 4));
  float* roww   = (float*)(ws + alloc((size_t)T_TOK * TOPK * 4));

  hipMemsetAsync(counts, 0, 64, stream);
  hipMemsetAsync(out, 0, (size_t)T_TOK * H_DIM * 4, stream);

  moe_gate<<<T_TOK / 256, 256, 0, stream>>>(x, gw, xb, tki, tkw, counts);

  moe_transpose2<<<dim3(F_DIM / 64, H_DIM / 64, N_EXP + N_SH), 256, 0, stream>>>(
      rw1, sw1, rw1T, sw1T, H_DIM, F_DIM);
  moe_transpose2<<<dim3(H_DIM / 64, F_DIM / 64, N_EXP + N_SH), 256, 0, stream>>>(
      rw2, sw2, rw2T, sw2T, F_DIM, H_DIM);

  moe_offsets<<<1, 64, 0, stream>>>(counts, offs, cursor);
  moe_build_rows<<<T_TOK / 256, 256, 0, stream>>>(tki, tkw, cursor, rowsl, roww);

  moe_gemm1<<<dim3(F_DIM / 128, T_TOK / 128, N_EXP + N_SH), 256, 0, stream>>>(
      xb, rw1T, sw1T, rb1, sb1, counts, offs, rowsl, h_rout, h_sh);
  moe_gemm2<<<dim3(H_DIM / 128, T_TOK / 128, N_EXP + N_SH), 256, 0, stream>>>(
      h_rout, h_sh, rw2T, sw2T, rb2, sb2, counts, offs, rowsl, roww, out);
}